// Round 1
// baseline (56.484 us; speedup 1.0000x reference)
//
#include <hip/hip_runtime.h>

// PoseLoss: memory-bound streaming reduction over B=2^20 samples.
// per-sample bytes: 3*(3+4)*4 + 7*4 = 112 B read. Two-pass deterministic
// reduction: block partials -> d_ws, then single-block final -> d_out.

#define W1_XYZ 0.3f
#define W2_XYZ 0.3f
#define W3_XYZ 1.0f
#define W1_WPQR 150.0f
#define W2_WPQR 150.0f
#define W3_WPQR 500.0f
#define EPSF 1e-12f

constexpr int B_TOTAL = 1048576;
constexpr int SPT = 4;          // samples per thread -> whole float4s for all arrays
constexpr int BLOCK = 256;
constexpr int NBLOCKS = B_TOTAL / (SPT * BLOCK);  // 1024

__global__ __launch_bounds__(BLOCK) void pose_loss_partial(
    const float* __restrict__ p1x, const float* __restrict__ p1q,
    const float* __restrict__ p2x, const float* __restrict__ p2q,
    const float* __restrict__ p3x, const float* __restrict__ p3q,
    const float* __restrict__ gt, float* __restrict__ partial)
{
    const int t = blockIdx.x * BLOCK + threadIdx.x;
    const long s0 = (long)t * SPT;   // first sample of this thread

    // register staging: all indices compile-time after unroll
    __attribute__((aligned(16))) float x1[12], x2[12], x3[12];
    __attribute__((aligned(16))) float q1[16], q2[16], q3[16];
    __attribute__((aligned(16))) float g[28];

    {
        const float4* v;
        v = reinterpret_cast<const float4*>(p1x + s0 * 3);
        #pragma unroll
        for (int i = 0; i < 3; ++i) reinterpret_cast<float4*>(x1)[i] = v[i];
        v = reinterpret_cast<const float4*>(p2x + s0 * 3);
        #pragma unroll
        for (int i = 0; i < 3; ++i) reinterpret_cast<float4*>(x2)[i] = v[i];
        v = reinterpret_cast<const float4*>(p3x + s0 * 3);
        #pragma unroll
        for (int i = 0; i < 3; ++i) reinterpret_cast<float4*>(x3)[i] = v[i];
        v = reinterpret_cast<const float4*>(p1q + s0 * 4);
        #pragma unroll
        for (int i = 0; i < 4; ++i) reinterpret_cast<float4*>(q1)[i] = v[i];
        v = reinterpret_cast<const float4*>(p2q + s0 * 4);
        #pragma unroll
        for (int i = 0; i < 4; ++i) reinterpret_cast<float4*>(q2)[i] = v[i];
        v = reinterpret_cast<const float4*>(p3q + s0 * 4);
        #pragma unroll
        for (int i = 0; i < 4; ++i) reinterpret_cast<float4*>(q3)[i] = v[i];
        v = reinterpret_cast<const float4*>(gt + s0 * 7);
        #pragma unroll
        for (int i = 0; i < 7; ++i) reinterpret_cast<float4*>(g)[i] = v[i];
    }

    float acc = 0.0f;
    #pragma unroll
    for (int j = 0; j < SPT; ++j) {
        const float px = g[7*j+0], py = g[7*j+1], pz = g[7*j+2];
        float qa = g[7*j+3], qb = g[7*j+4], qc = g[7*j+5], qd = g[7*j+6];
        const float qn = sqrtf(qa*qa + qb*qb + qc*qc + qd*qd);
        const float inv = 1.0f / fmaxf(qn, EPSF);
        qa *= inv; qb *= inv; qc *= inv; qd *= inv;

        float dx, dy, dz, dw;

        dx = x1[3*j+0] - px; dy = x1[3*j+1] - py; dz = x1[3*j+2] - pz;
        const float l1x = sqrtf(dx*dx + dy*dy + dz*dz);
        dw = q1[4*j+0] - qa; dx = q1[4*j+1] - qb; dy = q1[4*j+2] - qc; dz = q1[4*j+3] - qd;
        const float l1q = sqrtf(dw*dw + dx*dx + dy*dy + dz*dz);

        dx = x2[3*j+0] - px; dy = x2[3*j+1] - py; dz = x2[3*j+2] - pz;
        const float l2x = sqrtf(dx*dx + dy*dy + dz*dz);
        dw = q2[4*j+0] - qa; dx = q2[4*j+1] - qb; dy = q2[4*j+2] - qc; dz = q2[4*j+3] - qd;
        const float l2q = sqrtf(dw*dw + dx*dx + dy*dy + dz*dz);

        dx = x3[3*j+0] - px; dy = x3[3*j+1] - py; dz = x3[3*j+2] - pz;
        const float l3x = sqrtf(dx*dx + dy*dy + dz*dz);
        dw = q3[4*j+0] - qa; dx = q3[4*j+1] - qb; dy = q3[4*j+2] - qc; dz = q3[4*j+3] - qd;
        const float l3q = sqrtf(dw*dw + dx*dx + dy*dy + dz*dz);

        acc += W1_XYZ * (l1x + W1_WPQR * l1q)
             + W2_XYZ * (l2x + W2_WPQR * l2q)
             + W3_XYZ * (l3x + W3_WPQR * l3q);
    }

    // wave-64 reduction
    #pragma unroll
    for (int off = 32; off > 0; off >>= 1)
        acc += __shfl_down(acc, off);

    __shared__ float smem[BLOCK / 64];
    const int wid = threadIdx.x >> 6;
    if ((threadIdx.x & 63) == 0) smem[wid] = acc;
    __syncthreads();
    if (threadIdx.x == 0) {
        float s = 0.0f;
        #pragma unroll
        for (int w = 0; w < BLOCK / 64; ++w) s += smem[w];
        partial[blockIdx.x] = s;
    }
}

__global__ __launch_bounds__(BLOCK) void pose_loss_final(
    const float* __restrict__ partial, float* __restrict__ out, int n, float scale)
{
    float acc = 0.0f;
    for (int i = threadIdx.x; i < n; i += BLOCK) acc += partial[i];

    #pragma unroll
    for (int off = 32; off > 0; off >>= 1)
        acc += __shfl_down(acc, off);

    __shared__ float smem[BLOCK / 64];
    const int wid = threadIdx.x >> 6;
    if ((threadIdx.x & 63) == 0) smem[wid] = acc;
    __syncthreads();
    if (threadIdx.x == 0) {
        float s = 0.0f;
        #pragma unroll
        for (int w = 0; w < BLOCK / 64; ++w) s += smem[w];
        out[0] = s * scale;
    }
}

extern "C" void kernel_launch(void* const* d_in, const int* in_sizes, int n_in,
                              void* d_out, int out_size, void* d_ws, size_t ws_size,
                              hipStream_t stream) {
    const float* p1x = (const float*)d_in[0];
    const float* p1q = (const float*)d_in[1];
    const float* p2x = (const float*)d_in[2];
    const float* p2q = (const float*)d_in[3];
    const float* p3x = (const float*)d_in[4];
    const float* p3q = (const float*)d_in[5];
    const float* gt  = (const float*)d_in[6];
    float* out = (float*)d_out;
    float* partial = (float*)d_ws;   // NBLOCKS floats = 4 KB

    pose_loss_partial<<<NBLOCKS, BLOCK, 0, stream>>>(p1x, p1q, p2x, p2q, p3x, p3q, gt, partial);
    pose_loss_final<<<1, BLOCK, 0, stream>>>(partial, out, NBLOCKS, 1.0f / (float)B_TOTAL);
}

// Round 2
// 27.220 us; speedup vs baseline: 2.0751x; 2.0751x over previous
//
#include <hip/hip_runtime.h>

// PoseLoss: memory-bound streaming reduction over B=2^20 samples.
// Round 2: SPT=2 with float2 loads -> 8192 waves (32/CU, full wave capacity)
// to hide HBM latency. Round-1 SPT=4 was latency-bound (occ 33%, 3.0 TB/s).

#define W1_XYZ 0.3f
#define W2_XYZ 0.3f
#define W3_XYZ 1.0f
#define W1_WPQR 150.0f
#define W2_WPQR 150.0f
#define W3_WPQR 500.0f
#define EPSF 1e-12f

constexpr int B_TOTAL = 1048576;
constexpr int SPT = 2;          // samples per thread -> whole float2s for all arrays
constexpr int BLOCK = 256;
constexpr int NBLOCKS = B_TOTAL / (SPT * BLOCK);  // 2048

__global__ __launch_bounds__(BLOCK) void pose_loss_partial(
    const float* __restrict__ p1x, const float* __restrict__ p1q,
    const float* __restrict__ p2x, const float* __restrict__ p2q,
    const float* __restrict__ p3x, const float* __restrict__ p3q,
    const float* __restrict__ gt, float* __restrict__ partial)
{
    const long t = (long)blockIdx.x * BLOCK + threadIdx.x;

    // register staging, all float2 (8B) loads, lane-contiguous per stream
    __attribute__((aligned(8))) float x1[6], x2[6], x3[6];
    __attribute__((aligned(8))) float q1[8], q2[8], q3[8];
    __attribute__((aligned(8))) float g[14];

    {
        const float2* v;
        v = reinterpret_cast<const float2*>(p1x) + 3 * t;
        #pragma unroll
        for (int i = 0; i < 3; ++i) reinterpret_cast<float2*>(x1)[i] = v[i];
        v = reinterpret_cast<const float2*>(p2x) + 3 * t;
        #pragma unroll
        for (int i = 0; i < 3; ++i) reinterpret_cast<float2*>(x2)[i] = v[i];
        v = reinterpret_cast<const float2*>(p3x) + 3 * t;
        #pragma unroll
        for (int i = 0; i < 3; ++i) reinterpret_cast<float2*>(x3)[i] = v[i];
        v = reinterpret_cast<const float2*>(p1q) + 4 * t;
        #pragma unroll
        for (int i = 0; i < 4; ++i) reinterpret_cast<float2*>(q1)[i] = v[i];
        v = reinterpret_cast<const float2*>(p2q) + 4 * t;
        #pragma unroll
        for (int i = 0; i < 4; ++i) reinterpret_cast<float2*>(q2)[i] = v[i];
        v = reinterpret_cast<const float2*>(p3q) + 4 * t;
        #pragma unroll
        for (int i = 0; i < 4; ++i) reinterpret_cast<float2*>(q3)[i] = v[i];
        v = reinterpret_cast<const float2*>(gt) + 7 * t;
        #pragma unroll
        for (int i = 0; i < 7; ++i) reinterpret_cast<float2*>(g)[i] = v[i];
    }

    float acc = 0.0f;
    #pragma unroll
    for (int j = 0; j < SPT; ++j) {
        const float px = g[7*j+0], py = g[7*j+1], pz = g[7*j+2];
        float qa = g[7*j+3], qb = g[7*j+4], qc = g[7*j+5], qd = g[7*j+6];
        const float qn = sqrtf(qa*qa + qb*qb + qc*qc + qd*qd);
        const float inv = 1.0f / fmaxf(qn, EPSF);
        qa *= inv; qb *= inv; qc *= inv; qd *= inv;

        float dx, dy, dz, dw;

        dx = x1[3*j+0] - px; dy = x1[3*j+1] - py; dz = x1[3*j+2] - pz;
        const float l1x = sqrtf(dx*dx + dy*dy + dz*dz);
        dw = q1[4*j+0] - qa; dx = q1[4*j+1] - qb; dy = q1[4*j+2] - qc; dz = q1[4*j+3] - qd;
        const float l1q = sqrtf(dw*dw + dx*dx + dy*dy + dz*dz);

        dx = x2[3*j+0] - px; dy = x2[3*j+1] - py; dz = x2[3*j+2] - pz;
        const float l2x = sqrtf(dx*dx + dy*dy + dz*dz);
        dw = q2[4*j+0] - qa; dx = q2[4*j+1] - qb; dy = q2[4*j+2] - qc; dz = q2[4*j+3] - qd;
        const float l2q = sqrtf(dw*dw + dx*dx + dy*dy + dz*dz);

        dx = x3[3*j+0] - px; dy = x3[3*j+1] - py; dz = x3[3*j+2] - pz;
        const float l3x = sqrtf(dx*dx + dy*dy + dz*dz);
        dw = q3[4*j+0] - qa; dx = q3[4*j+1] - qb; dy = q3[4*j+2] - qc; dz = q3[4*j+3] - qd;
        const float l3q = sqrtf(dw*dw + dx*dx + dy*dy + dz*dz);

        acc += W1_XYZ * (l1x + W1_WPQR * l1q)
             + W2_XYZ * (l2x + W2_WPQR * l2q)
             + W3_XYZ * (l3x + W3_WPQR * l3q);
    }

    // wave-64 reduction
    #pragma unroll
    for (int off = 32; off > 0; off >>= 1)
        acc += __shfl_down(acc, off);

    __shared__ float smem[BLOCK / 64];
    const int wid = threadIdx.x >> 6;
    if ((threadIdx.x & 63) == 0) smem[wid] = acc;
    __syncthreads();
    if (threadIdx.x == 0) {
        float s = 0.0f;
        #pragma unroll
        for (int w = 0; w < BLOCK / 64; ++w) s += smem[w];
        partial[blockIdx.x] = s;
    }
}

__global__ __launch_bounds__(BLOCK) void pose_loss_final(
    const float* __restrict__ partial, float* __restrict__ out, int n, float scale)
{
    float acc = 0.0f;
    for (int i = threadIdx.x; i < n; i += BLOCK) acc += partial[i];

    #pragma unroll
    for (int off = 32; off > 0; off >>= 1)
        acc += __shfl_down(acc, off);

    __shared__ float smem[BLOCK / 64];
    const int wid = threadIdx.x >> 6;
    if ((threadIdx.x & 63) == 0) smem[wid] = acc;
    __syncthreads();
    if (threadIdx.x == 0) {
        float s = 0.0f;
        #pragma unroll
        for (int w = 0; w < BLOCK / 64; ++w) s += smem[w];
        out[0] = s * scale;
    }
}

extern "C" void kernel_launch(void* const* d_in, const int* in_sizes, int n_in,
                              void* d_out, int out_size, void* d_ws, size_t ws_size,
                              hipStream_t stream) {
    const float* p1x = (const float*)d_in[0];
    const float* p1q = (const float*)d_in[1];
    const float* p2x = (const float*)d_in[2];
    const float* p2q = (const float*)d_in[3];
    const float* p3x = (const float*)d_in[4];
    const float* p3q = (const float*)d_in[5];
    const float* gt  = (const float*)d_in[6];
    float* out = (float*)d_out;
    float* partial = (float*)d_ws;   // NBLOCKS floats = 8 KB

    pose_loss_partial<<<NBLOCKS, BLOCK, 0, stream>>>(p1x, p1q, p2x, p2q, p3x, p3q, gt, partial);
    pose_loss_final<<<1, BLOCK, 0, stream>>>(partial, out, NBLOCKS, 1.0f / (float)B_TOTAL);
}